// Round 12
// baseline (2422.556 us; speedup 1.0000x reference)
//
#include <hip/hip_runtime.h>

// AdEx Euler integration, fp32 port of the jax/numpy reference.
// Sequential scan over T=40000 steps; N=1024 neurons -> 16 waves on 16 CUs.
//
// MODEL (fits R1-R11): wall ~= 5.6 cyc x TOTAL instrs per step (VALU + SALU
// + VMEM) for a lone in-order wave; co-resident waves cannot reduce a wave's
// own serial time. R11 = 11 VALU + 2 stores + 4 SALU ptr-bumps + ~2.5
// prep/loop ~= 20 instrs -> 112 cyc ~= measured 111.5.
// Measured: trajectory bit-stable under increment-level rounding changes
// (R5-R11 all absmax EXACTLY 4.882812e-04).
//
// R1:  batched uniform I_ext loads                          8217 -> 7055 us
// R2:  divs -> fp64 reciprocal-mul (bit-exact)              7055 -> 4193 us
// R3:  burst-store buffering                                4193 -> 4007 us
// R4:  2 neurons/lane -> REGRESSED (2x instrs)              reverted
// R5:  raw v_exp_f32, folded log2e/delta_T                  4007 -> 2878 us
// R6:  fold dt/tau, dt/tau_w; all-f32 body                  2878 -> 2255 us
// R8:  6-dep V chain (pre-scaled exp, fma reassoc)          2255 -> 1885 us
// R9/R10: LDS staging -> REGRESSED (flush serializes)       reverted
// R11: linear-recurrence step, 11 VALU                      2299 -> 1858 us
// R12 (this): cut non-VALU instrs:
//   - step pairing: store even step at imm offset -4096 (legal min of the
//     13-bit signed global offset; row stride N*4 = 4096 exactly), bump
//     each base by 2N per 2 steps  -> 4 SALU/step -> 2
//   - batch prep as single fma: A = fmaf(cRI, I, cVr2), constants f64-folded
//   - drop redundant lane clamp
//   Budget ~16.5 instrs -> predict ~92 cyc/step.

__device__ __forceinline__ float exp2_raw(float u) {
    float r;
    asm("v_exp_f32 %0, %1" : "=v"(r) : "v"(u));   // r = 2^u, ~1 ulp
    return r;
}

__global__ void __launch_bounds__(64, 1) adex_kernel(
    const float* __restrict__ I_ext,
    const float* __restrict__ V0,
    const float* __restrict__ w0,
    const float* __restrict__ p_V_rest,
    const float* __restrict__ p_V_reset,
    const float* __restrict__ p_V_T,
    const float* __restrict__ p_V_thres,
    const float* __restrict__ p_delta_T,
    const float* __restrict__ p_R,
    const float* __restrict__ p_tau,
    const float* __restrict__ p_tau_w,
    const float* __restrict__ p_a,
    const float* __restrict__ p_b,
    float* __restrict__ out,
    int T, int N)
{
#pragma clang fp contract(off)
    const int l     = threadIdx.x;            // 0..63
    const int nbase = blockIdx.x * 64;        // grid = N/64 exactly
    const int n     = nbase + l;

    const float V_rest  = *p_V_rest;
    const float V_reset = *p_V_reset;
    const float V_T     = *p_V_T;
    const float V_thres = *p_V_thres;
    const float delta_T = *p_delta_T;
    const float R       = *p_R;
    const float tau     = *p_tau;
    const float tau_w   = *p_tau_w;
    const float a       = *p_a;
    const float b       = *p_b;
    const float dt      = 5e-5f;

    // All constants folded in f64, rounded once to f32.
    const double dT   = (double)delta_T;
    const double dcv  = (double)dt / (double)tau;      // dt/tau
    const double dcw  = (double)dt / (double)tau_w;    // dt/tau_w
    const double l2e  = 1.4426950408889634;

    const float c_exp = (float)(l2e / dT);
    const float c2    = (float)(log2(dT * dcv) - (double)V_T * (l2e / dT));
    const float alpha = (float)(1.0 - dcv);
    const float ncRv  = (float)(-dcv * (double)R);
    const float beta  = (float)(1.0 - dcw);
    const float gamma = (float)((double)a * dcw);
    const float delta = (float)(-(double)a * dcw * (double)V_rest);
    const float cRI   = (float)(dcv * (double)R);       // (dt/tau)*R
    const float cVr2  = (float)(dcv * (double)V_rest);  // (dt/tau)*V_rest

    float V = V0[n];
    float w = w0[n];

    // Store bases point at the ODD row of each step pair; even step stores
    // at byte offset -4096 (= -N floats), odd at 0. Bump 2N per pair.
    float* outVb = out + nbase + (size_t)N;
    float* outWb = out + (size_t)T * N + nbase + (size_t)N;

    // One Euler step; OFF = -N (even) or 0 (odd). 11 VALU + 2 stores.
#define ADEX_STEP(Ar2_k, OFF)                                       \
    {                                                               \
        outVb[(OFF) + l] = V;                                       \
        outWb[(OFF) + l] = w;                                       \
        float ex3 = exp2_raw(fmaf(V, c_exp, c2));                   \
        float m1  = fmaf(alpha, V, (Ar2_k));                        \
        float m2  = fmaf(ncRv, w, m1);                              \
        float Vn  = m2 + ex3;                                       \
        float t2  = fmaf(gamma, V, delta);                          \
        float wn  = fmaf(beta, w, t2);                              \
        bool  spike = V > V_thres;                                  \
        float wns = wn + b;                                         \
        Vn = spike ? V_reset : Vn;                                  \
        wn = spike ? wns : wn;                                      \
        V = Vn;                                                     \
        w = wn;                                                     \
    }

    // Double-buffered uniform I batches: Ar2 = fmaf(cRI, I, cVr2) (single
    // fma; increment-ulp fold, proven class). I_ext has T+5 elements;
    // prefetch base clamped so max index <= T+4.
    float A[16], B[16];
#pragma unroll
    for (int j = 0; j < 16; ++j) A[j] = fmaf(cRI, I_ext[j], cVr2);

    for (int kb = 0; kb < T; kb += 32) {
        // prefetch B = I[kb+16 .. kb+31]  (kb <= T-32 -> max idx T-1, ok)
#pragma unroll
        for (int j = 0; j < 16; ++j)
            B[j] = fmaf(cRI, I_ext[kb + 16 + j], cVr2);

#pragma unroll
        for (int j = 0; j < 16; j += 2) {
            ADEX_STEP(A[j],     -N);
            ADEX_STEP(A[j + 1],  0);
            outVb += 2 * N;
            outWb += 2 * N;
        }

        // prefetch A = I[kb+32 .. kb+47], clamped (pb+15 <= T+4)
        {
            int pb = kb + 32;
            if (pb > T - 11) pb = T - 11;
#pragma unroll
            for (int j = 0; j < 16; ++j)
                A[j] = fmaf(cRI, I_ext[pb + j], cVr2);
        }

#pragma unroll
        for (int j = 0; j < 16; j += 2) {
            ADEX_STEP(B[j],     -N);
            ADEX_STEP(B[j + 1],  0);
            outVb += 2 * N;
            outWb += 2 * N;
        }
    }
#undef ADEX_STEP
}

extern "C" void kernel_launch(void* const* d_in, const int* in_sizes, int n_in,
                              void* d_out, int out_size, void* d_ws, size_t ws_size,
                              hipStream_t stream) {
    const float* I_ext = (const float*)d_in[0];
    const float* V0    = (const float*)d_in[1];
    const float* w0    = (const float*)d_in[2];

    const int N = in_sizes[1];          // 1024 (multiple of 64)
    const int T = out_size / (2 * N);   // 40000

    const int block = 64;
    const int grid  = N / block;        // 16 blocks

    adex_kernel<<<grid, block, 0, stream>>>(
        I_ext, V0, w0,
        (const float*)d_in[3],  // V_rest
        (const float*)d_in[4],  // V_reset
        (const float*)d_in[5],  // V_T
        (const float*)d_in[6],  // V_thres
        (const float*)d_in[7],  // delta_T
        (const float*)d_in[8],  // R
        (const float*)d_in[9],  // tau
        (const float*)d_in[10], // tau_w
        (const float*)d_in[11], // a
        (const float*)d_in[12], // b
        (float*)d_out, T, N);
}

// Round 13
// 1994.209 us; speedup vs baseline: 1.2148x; 1.2148x over previous
//
#include <hip/hip_runtime.h>

// AdEx Euler integration, fp32 port of the jax/numpy reference.
// T=40000 sequential steps; N=1024 neurons -> 16 producer waves on 16 CUs.
//
// MODEL (fits R1-R12): wall ~= 5.6 cyc x TOTAL instrs/step on the lone
// in-order wave that carries the recurrence. Latency hiding across waves
// does not apply to a serial chain; every instr removed from the producer
// wave pays ~5.6 cyc. R12's pairing failed mechanically (runtime N killed
// the imm-offset fold; VGPR 28->60 of address math).
// Measured: trajectory bit-stable under increment-level rounding changes
// (R5-R12 all absmax EXACTLY 4.882812e-04).
//
// R11: linear-recurrence step, 11 VALU + 2 stores + bumps   1858 us (best)
// R13 (this): producer/consumer wave split (128-thr block = 2 waves):
//   producer: 11 VALU + 1 ds_write_b64 per step (V,w as float2; buf/step
//     LDS offsets compile-time imms -> zero addr arithmetic, no global-store
//     WAR on the recurrence wave).
//   consumer: polls LDS flag, drains 16-step batches to global (dword
//     stores, coalesced). Ring of 4 buffers + consumed-flag back-pressure
//     (slack 4) -> correct under any wave scheduling, no barriers in loop.
//   Producer math bit-identical to R11.

__device__ __forceinline__ float exp2_raw(float u) {
    float r;
    asm("v_exp_f32 %0, %1" : "=v"(r) : "v"(u));   // r = 2^u, ~1 ulp
    return r;
}

// s_waitcnt lgkmcnt(0), vm/exp left at max (0xC07F encodes vmcnt=63,
// expcnt=7, lgkmcnt=0 in the CDNA s_waitcnt immediate layout).
#define LGKM0() __builtin_amdgcn_s_waitcnt(0xC07F)

__global__ void __launch_bounds__(128, 1) adex_pc_kernel(
    const float* __restrict__ I_ext,
    const float* __restrict__ V0,
    const float* __restrict__ w0,
    const float* __restrict__ p_V_rest,
    const float* __restrict__ p_V_reset,
    const float* __restrict__ p_V_T,
    const float* __restrict__ p_V_thres,
    const float* __restrict__ p_delta_T,
    const float* __restrict__ p_R,
    const float* __restrict__ p_tau,
    const float* __restrict__ p_tau_w,
    const float* __restrict__ p_a,
    const float* __restrict__ p_b,
    float* __restrict__ out,
    int T, int N)
{
#pragma clang fp contract(off)
    // Ring of 4 staged batches: [buf][step][lane] (V,w) pairs. 32 KiB.
    __shared__ float2 stage[4][16][64];
    __shared__ int    flags[2];          // [0]=produced batches, [1]=consumed

    const int tid   = threadIdx.x;
    const int l     = tid & 63;
    const int wave  = tid >> 6;
    const int nbase = blockIdx.x * 64;   // N % 64 == 0

    volatile int* vflags = (volatile int*)flags;
    if (tid < 2) flags[tid] = 0;
    __syncthreads();                     // once, at kernel start only

    const int NB = T >> 4;               // batches of 16 steps (T % 64 == 0)

    if (wave == 0) {
        // ---------------- producer: the serial recurrence ----------------
        const float V_rest  = *p_V_rest;
        const float V_reset = *p_V_reset;
        const float V_T     = *p_V_T;
        const float V_thres = *p_V_thres;
        const float delta_T = *p_delta_T;
        const float R       = *p_R;
        const float tau     = *p_tau;
        const float tau_w   = *p_tau_w;
        const float a       = *p_a;
        const float b       = *p_b;
        const float dt      = 5e-5f;

        // Constants folded in f64, rounded once to f32 (proven bit-neutral
        // class: increment-level perturbations).
        const double dT  = (double)delta_T;
        const double dcv = (double)dt / (double)tau;
        const double dcw = (double)dt / (double)tau_w;
        const double l2e = 1.4426950408889634;

        const float c_exp = (float)(l2e / dT);
        const float c2    = (float)(log2(dT * dcv) - (double)V_T * (l2e / dT));
        const float alpha = (float)(1.0 - dcv);
        const float ncRv  = (float)(-dcv * (double)R);
        const float beta  = (float)(1.0 - dcw);
        const float gamma = (float)((double)a * dcw);
        const float delta = (float)(-(double)a * dcw * (double)V_rest);
        const float cRI   = (float)(dcv * (double)R);
        const float cVr2  = (float)(dcv * (double)V_rest);

        float V = V0[nbase + l];
        float w = w0[nbase + l];

        // One step: 1 ds_write_b64 (compile-time offsets) + 11 VALU.
#define ADEX_STEP(BUF, S, Ar2_k)                                    \
        {                                                           \
            stage[BUF][S][l] = make_float2(V, w);                   \
            float ex3 = exp2_raw(fmaf(V, c_exp, c2));               \
            float m1  = fmaf(alpha, V, (Ar2_k));                    \
            float m2  = fmaf(ncRv, w, m1);                          \
            float Vn  = m2 + ex3;                                   \
            float t2  = fmaf(gamma, V, delta);                      \
            float wn  = fmaf(beta, w, t2);                          \
            bool  spike = V > V_thres;                              \
            float wns = wn + b;                                     \
            Vn = spike ? V_reset : Vn;                              \
            wn = spike ? wns : wn;                                  \
            V = Vn;                                                 \
            w = wn;                                                 \
        }

        // One 16-step batch into ring buffer BUF; back-pressure slack 4.
#define PRODUCE(BUF, ARR, OFF)                                      \
        {                                                           \
            while (vflags[1] < pi - 3) __builtin_amdgcn_s_sleep(2); \
            asm volatile("" ::: "memory");                          \
            _Pragma("unroll")                                       \
            for (int s = 0; s < 16; ++s) ADEX_STEP(BUF, s, ARR[(OFF) + s]); \
            LGKM0();                                                \
            asm volatile("" ::: "memory");                          \
            ++pi;                                                   \
            vflags[0] = pi;                                         \
        }

        // Double-buffered uniform I batches of 32: Ar2 = fmaf(cRI, I, cVr2).
        // I_ext has T+5 elements; final prefetch clamped (pb+31 <= T+4).
        float A[32], B[32];
#pragma unroll
        for (int j = 0; j < 32; ++j) A[j] = fmaf(cRI, I_ext[j], cVr2);

        int pi = 0;
        for (int kb = 0; kb < T; kb += 64) {
            // prefetch B = I[kb+32 .. kb+63] (kb <= T-64 -> max idx T-1)
#pragma unroll
            for (int j = 0; j < 32; ++j)
                B[j] = fmaf(cRI, I_ext[kb + 32 + j], cVr2);

            PRODUCE(0, A, 0);
            PRODUCE(1, A, 16);

            // prefetch A = I[kb+64 .. kb+95], clamped so pb+31 <= T+4
            {
                int pb = kb + 64;
                if (pb > T - 27) pb = T - 27;
#pragma unroll
                for (int j = 0; j < 32; ++j)
                    A[j] = fmaf(cRI, I_ext[pb + j], cVr2);
            }

            PRODUCE(2, B, 0);
            PRODUCE(3, B, 16);
        }
#undef PRODUCE
#undef ADEX_STEP
    } else {
        // ---------------- consumer: drain LDS -> global ----------------
        float* outV = out + nbase + l;
        float* outW = out + (size_t)T * N + nbase + l;

        for (int ci = 0; ci < NB; ++ci) {
            while (vflags[0] < ci + 1) __builtin_amdgcn_s_sleep(2);
            asm volatile("" ::: "memory");
            const int buf = ci & 3;
#pragma unroll
            for (int s = 0; s < 16; ++s) {
                float2 vw = stage[buf][s][l];
                *outV = vw.x;
                *outW = vw.y;
                outV += N;
                outW += N;
            }
            asm volatile("" ::: "memory");
            vflags[1] = ci + 1;
        }
    }
}

// Fallback: R11's single-wave kernel (known-good 1858 us) for shapes that
// don't meet the producer/consumer preconditions.
__global__ void __launch_bounds__(64, 1) adex_fallback_kernel(
    const float* __restrict__ I_ext,
    const float* __restrict__ V0,
    const float* __restrict__ w0,
    const float* __restrict__ p_V_rest,
    const float* __restrict__ p_V_reset,
    const float* __restrict__ p_V_T,
    const float* __restrict__ p_V_thres,
    const float* __restrict__ p_delta_T,
    const float* __restrict__ p_R,
    const float* __restrict__ p_tau,
    const float* __restrict__ p_tau_w,
    const float* __restrict__ p_a,
    const float* __restrict__ p_b,
    float* __restrict__ out,
    int T, int N)
{
#pragma clang fp contract(off)
    const int l     = threadIdx.x;
    const int nbase = blockIdx.x * 64;
    int n = nbase + l;
    if (n >= N) n = N - 1;

    const float V_rest  = *p_V_rest;
    const float V_reset = *p_V_reset;
    const float V_T     = *p_V_T;
    const float V_thres = *p_V_thres;
    const float delta_T = *p_delta_T;
    const float R       = *p_R;
    const float tau     = *p_tau;
    const float tau_w   = *p_tau_w;
    const float a       = *p_a;
    const float b       = *p_b;
    const float dt      = 5e-5f;

    const double dT  = (double)delta_T;
    const double dcv = (double)dt / (double)tau;
    const double dcw = (double)dt / (double)tau_w;
    const double l2e = 1.4426950408889634;

    const float c_exp = (float)(l2e / dT);
    const float c2    = (float)(log2(dT * dcv) - (double)V_T * (l2e / dT));
    const float alpha = (float)(1.0 - dcv);
    const float ncRv  = (float)(-dcv * (double)R);
    const float beta  = (float)(1.0 - dcw);
    const float gamma = (float)((double)a * dcw);
    const float delta = (float)(-(double)a * dcw * (double)V_rest);
    const float cRI   = (float)(dcv * (double)R);
    const float cVr2  = (float)(dcv * (double)V_rest);

    float V = V0[n];
    float w = w0[n];

    float* outVb = out + nbase;
    float* outWb = out + (size_t)T * N + nbase;

#define ADEX_STEP(Ar2_k)                                            \
    {                                                               \
        outVb[l] = V;                                               \
        outWb[l] = w;                                               \
        outVb += N;                                                 \
        outWb += N;                                                 \
        float ex3 = exp2_raw(fmaf(V, c_exp, c2));                   \
        float m1  = fmaf(alpha, V, (Ar2_k));                        \
        float m2  = fmaf(ncRv, w, m1);                              \
        float Vn  = m2 + ex3;                                       \
        float t2  = fmaf(gamma, V, delta);                          \
        float wn  = fmaf(beta, w, t2);                              \
        bool  spike = V > V_thres;                                  \
        float wns = wn + b;                                         \
        Vn = spike ? V_reset : Vn;                                  \
        wn = spike ? wns : wn;                                      \
        V = Vn;                                                     \
        w = wn;                                                     \
    }

    float A[16], B[16];
#pragma unroll
    for (int j = 0; j < 16; ++j) A[j] = fmaf(cRI, I_ext[j], cVr2);

    for (int kb = 0; kb < T; kb += 32) {
#pragma unroll
        for (int j = 0; j < 16; ++j)
            B[j] = fmaf(cRI, I_ext[kb + 16 + j], cVr2);
#pragma unroll
        for (int j = 0; j < 16; ++j) ADEX_STEP(A[j]);
        {
            int pb = kb + 32;
            if (pb > T - 11) pb = T - 11;
#pragma unroll
            for (int j = 0; j < 16; ++j)
                A[j] = fmaf(cRI, I_ext[pb + j], cVr2);
        }
#pragma unroll
        for (int j = 0; j < 16; ++j) ADEX_STEP(B[j]);
    }
#undef ADEX_STEP
}

extern "C" void kernel_launch(void* const* d_in, const int* in_sizes, int n_in,
                              void* d_out, int out_size, void* d_ws, size_t ws_size,
                              hipStream_t stream) {
    const float* I_ext = (const float*)d_in[0];
    const float* V0    = (const float*)d_in[1];
    const float* w0    = (const float*)d_in[2];

    const int N = in_sizes[1];          // 1024 (multiple of 64)
    const int T = out_size / (2 * N);   // 40000 (multiple of 64)

    if ((N % 64 == 0) && (T % 64 == 0)) {
        adex_pc_kernel<<<N / 64, 128, 0, stream>>>(
            I_ext, V0, w0,
            (const float*)d_in[3], (const float*)d_in[4], (const float*)d_in[5],
            (const float*)d_in[6], (const float*)d_in[7], (const float*)d_in[8],
            (const float*)d_in[9], (const float*)d_in[10], (const float*)d_in[11],
            (const float*)d_in[12], (float*)d_out, T, N);
    } else {
        adex_fallback_kernel<<<(N + 63) / 64, 64, 0, stream>>>(
            I_ext, V0, w0,
            (const float*)d_in[3], (const float*)d_in[4], (const float*)d_in[5],
            (const float*)d_in[6], (const float*)d_in[7], (const float*)d_in[8],
            (const float*)d_in[9], (const float*)d_in[10], (const float*)d_in[11],
            (const float*)d_in[12], (float*)d_out, T, N);
    }
}

// Round 14
// 1902.766 us; speedup vs baseline: 1.2732x; 1.0481x over previous
//
#include <hip/hip_runtime.h>

// AdEx Euler integration, fp32 port of the jax/numpy reference.
// T=40000 sequential steps; N=1024 neurons -> 16 producer waves on 16 CUs.
//
// MODEL (fits R1-R13): a lone in-order wave dispatches ~1 instr / 5.6 cyc
// REGARDLESS of dependency structure (R4: 2 independent chains, same
// cadence) -> dispatch-bound. Wall = 5.6 x producer-instrs/step + per-batch
// stall amortization. Only levers: fewer producer instrs, fewer stalls.
// Measured: trajectory bit-stable under increment-level rounding changes
// (R5-R13 all absmax EXACTLY 4.882812e-04).
//
// R11: minimal linear-recurrence step (11 VALU)             1858 us
// R13: producer/consumer wave split, 16-step LDS ring       1727 us
// R14 (this): amortization cuts, math untouched:
//   - 2 steps packed per ds_write_b128 (0.5 staging instr/step)
//   - 32-step batches (ring 4 x 32 x 64 lanes x 16B = 64 KiB): poll /
//     LGKM0 / flag / branch overhead halves; poll ds_read latency ~130 cyc
//     amortizes to ~4 cyc/step
//   - ring-slot base once per buffer; per-pair DS offsets compile-time

__device__ __forceinline__ float exp2_raw(float u) {
    float r;
    asm("v_exp_f32 %0, %1" : "=v"(r) : "v"(u));   // r = 2^u, ~1 ulp
    return r;
}

// s_waitcnt lgkmcnt(0) (0xC07F = vmcnt max, expcnt max, lgkmcnt 0).
#define LGKM0() __builtin_amdgcn_s_waitcnt(0xC07F)

__global__ void __launch_bounds__(128, 1) adex_pc_kernel(
    const float* __restrict__ I_ext,
    const float* __restrict__ V0,
    const float* __restrict__ w0,
    const float* __restrict__ p_V_rest,
    const float* __restrict__ p_V_reset,
    const float* __restrict__ p_V_T,
    const float* __restrict__ p_V_thres,
    const float* __restrict__ p_delta_T,
    const float* __restrict__ p_R,
    const float* __restrict__ p_tau,
    const float* __restrict__ p_tau_w,
    const float* __restrict__ p_a,
    const float* __restrict__ p_b,
    float* __restrict__ out,
    int T, int N)
{
#pragma clang fp contract(off)
    // Ring of 4 buffers x 16 step-pairs x 64 lanes x float4 = 64 KiB.
    __shared__ float4 stage[4][16][64];
    __shared__ int    flags[2];          // [0]=produced bufs, [1]=consumed

    const int tid   = threadIdx.x;
    const int l     = tid & 63;
    const int wave  = tid >> 6;
    const int nbase = blockIdx.x * 64;   // N % 64 == 0

    volatile int* vflags = (volatile int*)flags;
    if (tid < 2) flags[tid] = 0;
    __syncthreads();                     // once, at kernel start only

    const int NB = T >> 5;               // 32-step buffers (T % 64 == 0)

    if (wave == 0) {
        // ---------------- producer: the serial recurrence ----------------
        const float V_rest  = *p_V_rest;
        const float V_reset = *p_V_reset;
        const float V_T     = *p_V_T;
        const float V_thres = *p_V_thres;
        const float delta_T = *p_delta_T;
        const float R       = *p_R;
        const float tau     = *p_tau;
        const float tau_w   = *p_tau_w;
        const float a       = *p_a;
        const float b       = *p_b;
        const float dt      = 5e-5f;

        // Constants folded in f64, rounded once to f32 (proven bit-neutral
        // class: increment-level perturbations, R5-R13).
        const double dT  = (double)delta_T;
        const double dcv = (double)dt / (double)tau;
        const double dcw = (double)dt / (double)tau_w;
        const double l2e = 1.4426950408889634;

        const float c_exp = (float)(l2e / dT);
        const float c2    = (float)(log2(dT * dcv) - (double)V_T * (l2e / dT));
        const float alpha = (float)(1.0 - dcv);
        const float ncRv  = (float)(-dcv * (double)R);
        const float beta  = (float)(1.0 - dcw);
        const float gamma = (float)((double)a * dcw);
        const float delta = (float)(-(double)a * dcw * (double)V_rest);
        const float cRI   = (float)(dcv * (double)R);
        const float cVr2  = (float)(dcv * (double)V_rest);

        float V = V0[nbase + l];
        float w = w0[nbase + l];

        // Pure math step, 11 VALU (bit-identical to R11/R13).
#define ADEX_MATH(Ar2_k)                                            \
        {                                                           \
            float ex3 = exp2_raw(fmaf(V, c_exp, c2));               \
            float m1  = fmaf(alpha, V, (Ar2_k));                    \
            float m2  = fmaf(ncRv, w, m1);                          \
            float Vn  = m2 + ex3;                                   \
            float t2  = fmaf(gamma, V, delta);                      \
            float wn  = fmaf(beta, w, t2);                          \
            bool  spike = V > V_thres;                              \
            float wns = wn + b;                                     \
            Vn = spike ? V_reset : Vn;                              \
            wn = spike ? wns : wn;                                  \
            V = Vn;                                                 \
            w = wn;                                                 \
        }

        // One 32-step buffer: 16 pairs, each 22 VALU + 1 ds_write_b128.
        // Slot base computed once (runtime pi&3); per-pair offset s*1024 B
        // is a compile-time DS imm. Back-pressure slack = 4 buffers.
#define PRODUCE(ARR)                                                \
        {                                                           \
            while (vflags[1] < pi - 3) __builtin_amdgcn_s_sleep(2); \
            asm volatile("" ::: "memory");                          \
            float4* sb = &stage[pi & 3][0][l];                      \
            _Pragma("unroll")                                       \
            for (int s = 0; s < 16; ++s) {                          \
                float Va = V, wa = w;                               \
                ADEX_MATH(ARR[2 * s]);                              \
                float Vb = V, wb = w;                               \
                ADEX_MATH(ARR[2 * s + 1]);                          \
                sb[s * 64] = make_float4(Va, wa, Vb, wb);           \
            }                                                       \
            LGKM0();                                                \
            asm volatile("" ::: "memory");                          \
            ++pi;                                                   \
            vflags[0] = pi;                                         \
        }

        // Double-buffered uniform I batches of 32 (one buffer each):
        // Ar2 = fmaf(cRI, I, cVr2). I_ext has T+5 elements; final prefetch
        // clamped so pb+31 <= T+4.
        float A[32], B[32];
#pragma unroll
        for (int j = 0; j < 32; ++j) A[j] = fmaf(cRI, I_ext[j], cVr2);

        int pi = 0;
        for (int kb = 0; kb < T; kb += 64) {
            // prefetch B = I[kb+32 .. kb+63] (kb <= T-64 -> max idx T-1)
#pragma unroll
            for (int j = 0; j < 32; ++j)
                B[j] = fmaf(cRI, I_ext[kb + 32 + j], cVr2);

            PRODUCE(A);

            // prefetch A = I[kb+64 .. kb+95], clamped so pb+31 <= T+4
            {
                int pb = kb + 64;
                if (pb > T - 27) pb = T - 27;
#pragma unroll
                for (int j = 0; j < 32; ++j)
                    A[j] = fmaf(cRI, I_ext[pb + j], cVr2);
            }

            PRODUCE(B);
        }
#undef PRODUCE
#undef ADEX_MATH
    } else {
        // ---------------- consumer: drain LDS -> global ----------------
        float* outV = out + nbase + l;
        float* outW = out + (size_t)T * N + nbase + l;

        for (int ci = 0; ci < NB; ++ci) {
            while (vflags[0] < ci + 1) __builtin_amdgcn_s_sleep(2);
            asm volatile("" ::: "memory");
            const float4* cb = &stage[ci & 3][0][l];
#pragma unroll
            for (int s = 0; s < 16; ++s) {
                float4 q = cb[s * 64];
                outV[0] = q.x;          // step 2s
                outW[0] = q.y;
                outV[N] = q.z;          // step 2s+1
                outW[N] = q.w;
                outV += 2 * N;
                outW += 2 * N;
            }
            // LDS reads retired (store data deps forced waits); slot free.
            asm volatile("" ::: "memory");
            vflags[1] = ci + 1;
        }
    }
}

// Fallback: R11-style single-wave kernel for shapes that don't meet the
// producer/consumer preconditions (N%64, T%64).
__global__ void __launch_bounds__(64, 1) adex_fallback_kernel(
    const float* __restrict__ I_ext,
    const float* __restrict__ V0,
    const float* __restrict__ w0,
    const float* __restrict__ p_V_rest,
    const float* __restrict__ p_V_reset,
    const float* __restrict__ p_V_T,
    const float* __restrict__ p_V_thres,
    const float* __restrict__ p_delta_T,
    const float* __restrict__ p_R,
    const float* __restrict__ p_tau,
    const float* __restrict__ p_tau_w,
    const float* __restrict__ p_a,
    const float* __restrict__ p_b,
    float* __restrict__ out,
    int T, int N)
{
#pragma clang fp contract(off)
    const int l     = threadIdx.x;
    const int nbase = blockIdx.x * 64;
    int n = nbase + l;
    if (n >= N) n = N - 1;

    const float V_rest  = *p_V_rest;
    const float V_reset = *p_V_reset;
    const float V_T     = *p_V_T;
    const float V_thres = *p_V_thres;
    const float delta_T = *p_delta_T;
    const float R       = *p_R;
    const float tau     = *p_tau;
    const float tau_w   = *p_tau_w;
    const float a       = *p_a;
    const float b       = *p_b;
    const float dt      = 5e-5f;

    const double dT  = (double)delta_T;
    const double dcv = (double)dt / (double)tau;
    const double dcw = (double)dt / (double)tau_w;
    const double l2e = 1.4426950408889634;

    const float c_exp = (float)(l2e / dT);
    const float c2    = (float)(log2(dT * dcv) - (double)V_T * (l2e / dT));
    const float alpha = (float)(1.0 - dcv);
    const float ncRv  = (float)(-dcv * (double)R);
    const float beta  = (float)(1.0 - dcw);
    const float gamma = (float)((double)a * dcw);
    const float delta = (float)(-(double)a * dcw * (double)V_rest);
    const float cRI   = (float)(dcv * (double)R);
    const float cVr2  = (float)(dcv * (double)V_rest);

    float V = V0[n];
    float w = w0[n];

    float* outVb = out + nbase;
    float* outWb = out + (size_t)T * N + nbase;

#define ADEX_STEP(Ar2_k)                                            \
    {                                                               \
        outVb[l] = V;                                               \
        outWb[l] = w;                                               \
        outVb += N;                                                 \
        outWb += N;                                                 \
        float ex3 = exp2_raw(fmaf(V, c_exp, c2));                   \
        float m1  = fmaf(alpha, V, (Ar2_k));                        \
        float m2  = fmaf(ncRv, w, m1);                              \
        float Vn  = m2 + ex3;                                       \
        float t2  = fmaf(gamma, V, delta);                          \
        float wn  = fmaf(beta, w, t2);                              \
        bool  spike = V > V_thres;                                  \
        float wns = wn + b;                                         \
        Vn = spike ? V_reset : Vn;                                  \
        wn = spike ? wns : wn;                                      \
        V = Vn;                                                     \
        w = wn;                                                     \
    }

    float A[16], B[16];
#pragma unroll
    for (int j = 0; j < 16; ++j) A[j] = fmaf(cRI, I_ext[j], cVr2);

    for (int kb = 0; kb < T; kb += 32) {
#pragma unroll
        for (int j = 0; j < 16; ++j)
            B[j] = fmaf(cRI, I_ext[kb + 16 + j], cVr2);
#pragma unroll
        for (int j = 0; j < 16; ++j) ADEX_STEP(A[j]);
        {
            int pb = kb + 32;
            if (pb > T - 11) pb = T - 11;
#pragma unroll
            for (int j = 0; j < 16; ++j)
                A[j] = fmaf(cRI, I_ext[pb + j], cVr2);
        }
#pragma unroll
        for (int j = 0; j < 16; ++j) ADEX_STEP(B[j]);
    }
#undef ADEX_STEP
}

extern "C" void kernel_launch(void* const* d_in, const int* in_sizes, int n_in,
                              void* d_out, int out_size, void* d_ws, size_t ws_size,
                              hipStream_t stream) {
    const float* I_ext = (const float*)d_in[0];
    const float* V0    = (const float*)d_in[1];
    const float* w0    = (const float*)d_in[2];

    const int N = in_sizes[1];          // 1024 (multiple of 64)
    const int T = out_size / (2 * N);   // 40000 (multiple of 64)

    if ((N % 64 == 0) && (T % 64 == 0)) {
        adex_pc_kernel<<<N / 64, 128, 0, stream>>>(
            I_ext, V0, w0,
            (const float*)d_in[3], (const float*)d_in[4], (const float*)d_in[5],
            (const float*)d_in[6], (const float*)d_in[7], (const float*)d_in[8],
            (const float*)d_in[9], (const float*)d_in[10], (const float*)d_in[11],
            (const float*)d_in[12], (float*)d_out, T, N);
    } else {
        adex_fallback_kernel<<<(N + 63) / 64, 64, 0, stream>>>(
            I_ext, V0, w0,
            (const float*)d_in[3], (const float*)d_in[4], (const float*)d_in[5],
            (const float*)d_in[6], (const float*)d_in[7], (const float*)d_in[8],
            (const float*)d_in[9], (const float*)d_in[10], (const float*)d_in[11],
            (const float*)d_in[12], (float*)d_out, T, N);
    }
}